// Round 1
// baseline (4527.314 us; speedup 1.0000x reference)
//
#include <hip/hip_runtime.h>
#include <stdint.h>

typedef unsigned short u16;

#define N_    64
#define CIN_  64
#define T_    256
#define V_    25
#define COUT_ 128
#define CI_   64
#define TT_   10
#define P_    250          // TT_*V_
#define NCH_  26           // ceil(T_/TT_)
#define NBLK3 (NCH_*N_)    // 1664
#define CNT_  409600.0f    // N_*T_*V_
#define EPS_  1e-5f

__device__ __forceinline__ u16 f2bf(float f) {
  uint32_t u = __float_as_uint(f);
  u += 0x7fffu + ((u >> 16) & 1u);   // RNE
  return (u16)(u >> 16);
}
__device__ __forceinline__ float bf2f(u16 h) { return __uint_as_float(((uint32_t)h) << 16); }
__device__ __forceinline__ float bflo(uint32_t w) { return __uint_as_float(w << 16); }
__device__ __forceinline__ float bfhi(uint32_t w) { return __uint_as_float(w & 0xffff0000u); }

// ---------------- K1: temporal means of x (forward / backward windows) ----------------
__global__ __launch_bounds__(256) void k_means(const float* __restrict__ x,
                                               float* __restrict__ mf, float* __restrict__ mb) {
  int i = blockIdx.x, n = blockIdx.y;
  const float* src = x + ((size_t)n * CIN_ + i) * T_ * V_;
  __shared__ float xs[T_ * V_];          // 25.6 KB
  __shared__ float pf[8][32], pb[8][32];
  for (int idx = threadIdx.x; idx < T_ * V_; idx += 256) xs[idx] = src[idx];
  __syncthreads();
  int v = threadIdx.x & 31, g = threadIdx.x >> 5;
  float sf = 0.f, sb = 0.f;
  if (v < V_) {
    for (int t = g; t < T_; t += 8) {
      float val = xs[t * V_ + v];
      if (t < T_ - 2) sf += val;
      if (t >= 2)     sb += val;
    }
  }
  pf[g][v] = sf; pb[g][v] = sb;
  __syncthreads();
  if (threadIdx.x < V_) {
    float af = 0.f, ab = 0.f;
    for (int gg = 0; gg < 8; gg++) { af += pf[gg][threadIdx.x]; ab += pb[gg][threadIdx.x]; }
    size_t o = ((size_t)n * CIN_ + i) * V_ + threadIdx.x;
    mf[o] = af * (1.0f / 254.0f);
    mb[o] = ab * (1.0f / 254.0f);
  }
}

// ---------------- K2: dynamic adjacency Rd' = alpha*tanh(P - Q + bm3), zb, yb ----------------
__global__ __launch_bounds__(256) void k_rd(
    const float* __restrict__ mf, const float* __restrict__ mb,
    const float* __restrict__ Wm1, const float* __restrict__ bm1,
    const float* __restrict__ Wm2, const float* __restrict__ bm2,
    const float* __restrict__ Wm3, const float* __restrict__ bm3,
    const float* __restrict__ bm4, const float* __restrict__ alpha,
    const float* __restrict__ A, const float* __restrict__ Al, const float* __restrict__ bp,
    u16* __restrict__ Rd, float* __restrict__ zb, float* __restrict__ yb) {
  int n = blockIdx.x;
  __shared__ float MfL[CIN_][V_], MbL[CIN_][V_], xfL[CI_][V_], xbL[CI_][V_];
  __shared__ float PL[COUT_ * V_], QL[COUT_ * V_];
  for (int idx = threadIdx.x; idx < CIN_ * V_; idx += 256) {
    MfL[idx / V_][idx % V_] = mf[(size_t)n * CIN_ * V_ + idx];
    MbL[idx / V_][idx % V_] = mb[(size_t)n * CIN_ * V_ + idx];
  }
  __syncthreads();
  for (int idx = threadIdx.x; idx < CI_ * V_; idx += 256) {
    int o = idx / V_, v = idx % V_;
    float af = bm1[o], ab = bm2[o];
    for (int i = 0; i < CIN_; i++) {
      af += Wm1[o * CIN_ + i] * MfL[i][v];
      ab += Wm2[o * CIN_ + i] * MbL[i][v];
    }
    xfL[o][v] = af; xbL[o][v] = ab;
  }
  __syncthreads();
  for (int idx = threadIdx.x; idx < COUT_ * V_; idx += 256) {
    int c = idx / V_, u = idx % V_;
    float p = 0.f, q = 0.f;
    for (int i = 0; i < CI_; i++) {
      p += Wm3[c * CI_ + i] * xbL[i][u];
      q += Wm3[c * CI_ + i] * xfL[i][u];
    }
    PL[idx] = p; QL[idx] = q;
  }
  __syncthreads();
  float al = alpha[0];
  for (int r = threadIdx.x; r < COUT_ * V_; r += 256) {
    int c = r / V_, u = r % V_;
    float pv = PL[r] + bm3[c];
    float acc = 0.f;
    size_t base = (((size_t)n * COUT_ + c) * V_ + u) * V_;
    for (int w = 0; w < V_; w++) {
      float val = al * tanhf(pv - QL[c * V_ + w]);
      Rd[base + w] = f2bf(val);
      acc += val;
    }
    zb[((size_t)n * COUT_ + c) * V_ + u] = bm4[c] * acc;
  }
  if (n == 0) {
    for (int r = threadIdx.x; r < COUT_ * V_; r += 256) {
      int c = r / V_, u = r % V_;
      float acc = 0.f;
      for (int s = 0; s < 3; s++) {
        float rb = 0.f;
        for (int v = 0; v < V_; v++) rb += A[(s * V_ + u) * V_ + v] + Al[(s * V_ + u) * V_ + v];
        acc += bp[s * COUT_ + c] * rb;
      }
      yb[r] = acc;
    }
  }
}

// ---------------- K3: main fused pass -> packed (y_pre, d) bf16 into d_out + stats ----------------
__global__ __launch_bounds__(256) void k_main(
    const float* __restrict__ x, const float* __restrict__ A, const float* __restrict__ Al,
    const float* __restrict__ Wp, const float* __restrict__ Wm4, const float* __restrict__ dW,
    const u16* __restrict__ Rd, const float* __restrict__ zb, const float* __restrict__ yb,
    uint32_t* __restrict__ outp, float* __restrict__ partials) {
  __shared__ alignas(16) uint32_t xsl[P_][36];  // x tile, bf16 pairs, k-contiguous; 36 KB
  __shared__ float BL[3][V_][26];               // A+Al, padded; 7.8 KB
  __shared__ u16   XpL[3][2][TT_][26];          // 3.1 KB
  __shared__ u16   XmL[2][TT_][26];             // 1.0 KB
  __shared__ u16   RdL[2][V_][26];              // 2.6 KB
  __shared__ float zbL[2][V_], ybL[2][V_];
  __shared__ float statsL[COUT_ * 4];           // 2 KB
  int tid = threadIdx.x;
  int tc = blockIdx.x, n = blockIdx.y;
  int t0 = tc * TT_;
  int pvalid = min(P_, (T_ - t0) * V_);

  // stage x tile (coalesced global, pack 2 bf16/word, transposed [pp][k])
  {
    const float* xb_ = x + (size_t)n * CIN_ * T_ * V_ + (size_t)t0 * V_;
    for (int idx = tid; idx < 32 * P_; idx += 256) {
      int kp = idx / P_, pp = idx % P_;
      float a = 0.f, b = 0.f;
      if (pp < pvalid) {
        a = xb_[(size_t)(2 * kp)     * T_ * V_ + pp];
        b = xb_[(size_t)(2 * kp + 1) * T_ * V_ + pp];
      }
      xsl[pp][kp] = ((uint32_t)f2bf(b) << 16) | (uint32_t)f2bf(a);
    }
  }
  for (int idx = tid; idx < 3 * V_ * V_; idx += 256) {
    int s = idx / (V_ * V_), r = idx % (V_ * V_);
    BL[s][r / V_][r % V_] = A[idx] + Al[idx];
  }
  for (int idx = tid; idx < COUT_ * 4; idx += 256) statsL[idx] = 0.f;
  __syncthreads();

  int slot = (tid < P_) ? tid : 0;
  int tt = slot / V_, q = slot % V_;
  bool act = tid < P_;
  bool valid = act && (t0 + tt < T_);

  for (int g = 0; g < COUT_ / 2; g++) {
    int c0 = 2 * g;
    const float* w0 = Wp  + (size_t)(0 * COUT_ + c0) * CIN_;
    const float* w1 = Wp  + (size_t)(1 * COUT_ + c0) * CIN_;
    const float* w2 = Wp  + (size_t)(2 * COUT_ + c0) * CIN_;
    const float* w3 = Wm4 + (size_t)c0 * CIN_;
    const float* w4 = dW  + (size_t)c0 * CIN_;
    float a00 = 0, a01 = 0, a02 = 0, a03 = 0, a04 = 0;
    float a10 = 0, a11 = 0, a12 = 0, a13 = 0, a14 = 0;
    const uint4* xrow = (const uint4*)&xsl[slot][0];
    #pragma unroll
    for (int j = 0; j < 8; j++) {
      uint4 wv = xrow[j];
      float xv[8] = { bflo(wv.x), bfhi(wv.x), bflo(wv.y), bfhi(wv.y),
                      bflo(wv.z), bfhi(wv.z), bflo(wv.w), bfhi(wv.w) };
      #pragma unroll
      for (int m = 0; m < 8; m++) {
        int k = j * 8 + m;
        float xm = xv[m];
        a00 = fmaf(w0[k], xm, a00); a01 = fmaf(w1[k], xm, a01); a02 = fmaf(w2[k], xm, a02);
        a03 = fmaf(w3[k], xm, a03); a04 = fmaf(w4[k], xm, a04);
        a10 = fmaf(w0[k + CIN_], xm, a10); a11 = fmaf(w1[k + CIN_], xm, a11);
        a12 = fmaf(w2[k + CIN_], xm, a12); a13 = fmaf(w3[k + CIN_], xm, a13);
        a14 = fmaf(w4[k + CIN_], xm, a14);
      }
    }
    if (act) {
      XpL[0][0][tt][q] = f2bf(a00); XpL[1][0][tt][q] = f2bf(a01); XpL[2][0][tt][q] = f2bf(a02);
      XmL[0][tt][q] = f2bf(a03);
      XpL[0][1][tt][q] = f2bf(a10); XpL[1][1][tt][q] = f2bf(a11); XpL[2][1][tt][q] = f2bf(a12);
      XmL[1][tt][q] = f2bf(a13);
    }
    for (int idx = tid; idx < 2 * V_ * 26; idx += 256) {
      int j = idx / (V_ * 26), r = idx - j * (V_ * 26);
      int u = r / 26, w = r - u * 26;
      RdL[j][u][w] = (w < V_) ? Rd[(((size_t)n * COUT_ + c0 + j) * V_ + u) * V_ + w] : (u16)0;
    }
    if (tid < 2 * V_) {
      int j = tid / V_, u = tid % V_;
      zbL[j][u] = zb[((size_t)n * COUT_ + c0 + j) * V_ + u];
      ybL[j][u] = yb[(c0 + j) * V_ + u];
    }
    __syncthreads();

    float y0 = ybL[0][q] + zbL[0][q];
    float y1 = ybL[1][q] + zbL[1][q];
    #pragma unroll
    for (int v = 0; v < V_; v++) {
      float b0 = BL[0][q][v], b1 = BL[1][q][v], b2 = BL[2][q][v];
      float xp00 = bf2f(XpL[0][0][tt][v]), xp10 = bf2f(XpL[1][0][tt][v]), xp20 = bf2f(XpL[2][0][tt][v]);
      float xp01 = bf2f(XpL[0][1][tt][v]), xp11 = bf2f(XpL[1][1][tt][v]), xp21 = bf2f(XpL[2][1][tt][v]);
      y0 = fmaf(b0, xp00, y0); y0 = fmaf(b1, xp10, y0); y0 = fmaf(b2, xp20, y0);
      y1 = fmaf(b0, xp01, y1); y1 = fmaf(b1, xp11, y1); y1 = fmaf(b2, xp21, y1);
      y0 = fmaf(bf2f(RdL[0][q][v]), bf2f(XmL[0][tt][v]), y0);
      y1 = fmaf(bf2f(RdL[1][q][v]), bf2f(XmL[1][tt][v]), y1);
    }
    float d0 = a04, d1 = a14;
    if (valid) {
      size_t o0 = (((size_t)n * COUT_ + c0) * T_ + (t0 + tt)) * V_ + q;
      outp[o0]                     = ((uint32_t)f2bf(d0) << 16) | (uint32_t)f2bf(y0);
      outp[o0 + (size_t)T_ * V_]   = ((uint32_t)f2bf(d1) << 16) | (uint32_t)f2bf(y1);
    }
    float s0 = valid ? y0 : 0.f, s1 = valid ? y0 * y0 : 0.f, s2 = valid ? d0 : 0.f, s3 = valid ? d0 * d0 : 0.f;
    float s4 = valid ? y1 : 0.f, s5 = valid ? y1 * y1 : 0.f, s6 = valid ? d1 : 0.f, s7 = valid ? d1 * d1 : 0.f;
    #pragma unroll
    for (int off = 32; off > 0; off >>= 1) {
      s0 += __shfl_xor(s0, off); s1 += __shfl_xor(s1, off);
      s2 += __shfl_xor(s2, off); s3 += __shfl_xor(s3, off);
      s4 += __shfl_xor(s4, off); s5 += __shfl_xor(s5, off);
      s6 += __shfl_xor(s6, off); s7 += __shfl_xor(s7, off);
    }
    if ((tid & 63) == 0) {
      atomicAdd(&statsL[(c0)     * 4 + 0], s0); atomicAdd(&statsL[(c0)     * 4 + 1], s1);
      atomicAdd(&statsL[(c0)     * 4 + 2], s2); atomicAdd(&statsL[(c0)     * 4 + 3], s3);
      atomicAdd(&statsL[(c0 + 1) * 4 + 0], s4); atomicAdd(&statsL[(c0 + 1) * 4 + 1], s5);
      atomicAdd(&statsL[(c0 + 1) * 4 + 2], s6); atomicAdd(&statsL[(c0 + 1) * 4 + 3], s7);
    }
    __syncthreads();
  }
  float* pdst = partials + (size_t)(n * NCH_ + tc) * (COUT_ * 4);
  for (int idx = tid; idx < COUT_ * 4; idx += 256) pdst[idx] = statsL[idx];
}

// ---------------- K4: reduce partials -> BN affine params ----------------
__global__ __launch_bounds__(512) void k_stats(
    const float* __restrict__ partials,
    const float* __restrict__ bn_g, const float* __restrict__ bn_b,
    const float* __restrict__ dn_g, const float* __restrict__ dn_b,
    float* __restrict__ params) {
  __shared__ float tot[COUT_ * 4];
  int tid = threadIdx.x;
  float s = 0.f;
  for (int b = 0; b < NBLK3; b++) s += partials[(size_t)b * (COUT_ * 4) + tid];
  tot[tid] = s;
  __syncthreads();
  if (tid < COUT_) {
    float sy = tot[tid * 4], syy = tot[tid * 4 + 1], sd = tot[tid * 4 + 2], sdd = tot[tid * 4 + 3];
    float muY = sy / CNT_, varY = syy / CNT_ - muY * muY;
    float muD = sd / CNT_, varD = sdd / CNT_ - muD * muD;
    float sY = bn_g[tid] * rsqrtf(varY + EPS_);
    float sD = dn_g[tid] * rsqrtf(varD + EPS_);
    float off = bn_b[tid] - muY * sY + dn_b[tid] - muD * sD;
    params[tid * 4 + 0] = sY; params[tid * 4 + 1] = sD; params[tid * 4 + 2] = off;
  }
}

// ---------------- K5: in-place finalize: relu(y*sY + d*sD + off) ----------------
__global__ __launch_bounds__(256) void k_final(uint32_t* __restrict__ io, const float* __restrict__ params) {
  int slab = blockIdx.x;             // n*COUT_ + c
  int c = slab & (COUT_ - 1);
  float sY = params[c * 4], sD = params[c * 4 + 1], off = params[c * 4 + 2];
  size_t base = (size_t)slab * (T_ * V_);
  #pragma unroll 5
  for (int j = 0; j < 25; j++) {
    size_t idx = base + j * 256 + threadIdx.x;
    uint32_t w = io[idx];
    float y = bf2f((u16)(w & 0xffffu));
    float d = bf2f((u16)(w >> 16));
    float val = fmaf(y, sY, fmaf(d, sD, off));
    io[idx] = __float_as_uint(fmaxf(val, 0.0f));
  }
}

extern "C" void kernel_launch(void* const* d_in, const int* in_sizes, int n_in,
                              void* d_out, int out_size, void* d_ws, size_t ws_size,
                              hipStream_t stream) {
  const float* x    = (const float*)d_in[0];
  const float* A    = (const float*)d_in[1];
  const float* Al   = (const float*)d_in[2];
  const float* Wp   = (const float*)d_in[3];
  const float* bp   = (const float*)d_in[4];
  const float* Wm1  = (const float*)d_in[5];
  const float* bm1  = (const float*)d_in[6];
  const float* Wm2  = (const float*)d_in[7];
  const float* bm2  = (const float*)d_in[8];
  const float* Wm3  = (const float*)d_in[9];
  const float* bm3  = (const float*)d_in[10];
  const float* Wm4  = (const float*)d_in[11];
  const float* bm4  = (const float*)d_in[12];
  const float* alpha= (const float*)d_in[13];
  const float* bn_g = (const float*)d_in[14];
  const float* bn_b = (const float*)d_in[15];
  const float* dW   = (const float*)d_in[16];
  const float* dn_g = (const float*)d_in[17];
  const float* dn_b = (const float*)d_in[18];

  // workspace layout (bytes, all 16B-aligned); total ~15.3 MB
  char* ws = (char*)d_ws;
  float* mf       = (float*)(ws + 0);              // 409600 B
  float* mb       = (float*)(ws + 409600);         // 409600 B
  u16*   Rd       = (u16*)  (ws + 819200);         // 10,240,000 B (bf16)
  float* zbuf     = (float*)(ws + 11059200);       // 819200 B
  float* ybuf     = (float*)(ws + 11878400);       // 12800 B
  float* partials = (float*)(ws + 11891200);       // 3,407,872 B
  float* params   = (float*)(ws + 15299072);       // 2048 B

  k_means<<<dim3(CIN_, N_), dim3(256), 0, stream>>>(x, mf, mb);
  k_rd<<<dim3(N_), dim3(256), 0, stream>>>(mf, mb, Wm1, bm1, Wm2, bm2, Wm3, bm3,
                                           bm4, alpha, A, Al, bp, Rd, zbuf, ybuf);
  k_main<<<dim3(NCH_, N_), dim3(256), 0, stream>>>(x, A, Al, Wp, Wm4, dW, Rd, zbuf, ybuf,
                                                   (uint32_t*)d_out, partials);
  k_stats<<<dim3(1), dim3(512), 0, stream>>>(partials, bn_g, bn_b, dn_g, dn_b, params);
  k_final<<<dim3(N_ * COUT_), dim3(256), 0, stream>>>((uint32_t*)d_out, params);
}

// Round 2
// 679.480 us; speedup vs baseline: 6.6629x; 6.6629x over previous
//
#include <hip/hip_runtime.h>
#include <stdint.h>

typedef unsigned short u16;
typedef unsigned int   u32;
typedef short bf16x8 __attribute__((ext_vector_type(8)));
typedef float f32x4  __attribute__((ext_vector_type(4)));

#define N_    64
#define CIN_  64
#define T_    256
#define V_    25
#define COUT_ 128
#define CI_   64
#define EPS_  1e-5f
#define CNT_  409600.0f

#define MFMA16(a,b,c) __builtin_amdgcn_mfma_f32_16x16x32_bf16((a),(b),(c),0,0,0)

__device__ __forceinline__ u16 f2bf(float f) {
  u32 u = __float_as_uint(f);
  u += 0x7fffu + ((u >> 16) & 1u);   // RNE
  return (u16)(u >> 16);
}
__device__ __forceinline__ float bf2f(u16 h) { return __uint_as_float(((u32)h) << 16); }

// ---------------- K0: pack weights to bf16 (W5 = [Wp s0;Wp s1;Wp s2;Wm4;dW], BsT = (A+Al)[s][u][v] padded) ----
__global__ __launch_bounds__(256) void k_pack(const float* __restrict__ Wp, const float* __restrict__ Wm4,
                                              const float* __restrict__ dW, const float* __restrict__ A,
                                              const float* __restrict__ Al,
                                              u16* __restrict__ w5, u16* __restrict__ bst) {
  int tid = threadIdx.x;
  for (int i = tid; i < 640 * 64; i += 256) {
    int r = i >> 6, k = i & 63;
    float v = (r < 384) ? Wp[i] : (r < 512) ? Wm4[(r - 384) * 64 + k] : dW[(r - 512) * 64 + k];
    w5[i] = f2bf(v);
  }
  for (int i = tid; i < 3 * 32 * 32; i += 256) {
    int s = i >> 10, rem = i & 1023, u = rem >> 5, v = rem & 31;
    float val = (u < 25 && v < 25) ? (A[(s * 25 + u) * 25 + v] + Al[(s * 25 + u) * 25 + v]) : 0.f;
    bst[i] = f2bf(val);
  }
}

// ---------------- K1: temporal means of x (forward / backward windows) ----------------
__global__ __launch_bounds__(256) void k_means(const float* __restrict__ x,
                                               float* __restrict__ mf, float* __restrict__ mb) {
  int i = blockIdx.x, n = blockIdx.y;
  const float* src = x + ((size_t)n * CIN_ + i) * T_ * V_;
  __shared__ float xs[T_ * V_];
  __shared__ float pf[8][32], pb[8][32];
  for (int idx = threadIdx.x; idx < T_ * V_; idx += 256) xs[idx] = src[idx];
  __syncthreads();
  int v = threadIdx.x & 31, g = threadIdx.x >> 5;
  float sf = 0.f, sb = 0.f;
  if (v < V_) {
    for (int t = g; t < T_; t += 8) {
      float val = xs[t * V_ + v];
      if (t < T_ - 2) sf += val;
      if (t >= 2)     sb += val;
    }
  }
  pf[g][v] = sf; pb[g][v] = sb;
  __syncthreads();
  if (threadIdx.x < V_) {
    float af = 0.f, ab = 0.f;
    for (int gg = 0; gg < 8; gg++) { af += pf[gg][threadIdx.x]; ab += pb[gg][threadIdx.x]; }
    size_t o = ((size_t)n * CIN_ + i) * V_ + threadIdx.x;
    mf[o] = af * (1.0f / 254.0f);
    mb[o] = ab * (1.0f / 254.0f);
  }
}

// ---------------- K2: Rd' = alpha*tanh(P - Q + bm3) (bf16, v-padded-32) + bias[n][c][u] ----------------
__global__ __launch_bounds__(256) void k_rd(
    const float* __restrict__ mf, const float* __restrict__ mb,
    const float* __restrict__ Wm1, const float* __restrict__ bm1,
    const float* __restrict__ Wm2, const float* __restrict__ bm2,
    const float* __restrict__ Wm3, const float* __restrict__ bm3,
    const float* __restrict__ bm4, const float* __restrict__ alpha,
    const float* __restrict__ A, const float* __restrict__ Al, const float* __restrict__ bp,
    u16* __restrict__ rdws, float* __restrict__ biasws) {
  int n = blockIdx.x;
  int tid = threadIdx.x;
  __shared__ float MfL[CIN_][V_], MbL[CIN_][V_], xfL[CI_][V_], xbL[CI_][V_];
  __shared__ float PL[COUT_ * V_], QL[COUT_ * V_], rsumL[3][V_];
  for (int idx = tid; idx < CIN_ * V_; idx += 256) {
    MfL[idx / V_][idx % V_] = mf[(size_t)n * CIN_ * V_ + idx];
    MbL[idx / V_][idx % V_] = mb[(size_t)n * CIN_ * V_ + idx];
  }
  if (tid < 75) {
    int s = tid / 25, u = tid % 25;
    float acc = 0.f;
    for (int v = 0; v < 25; v++) acc += A[(s * 25 + u) * 25 + v] + Al[(s * 25 + u) * 25 + v];
    rsumL[s][u] = acc;
  }
  __syncthreads();
  for (int idx = tid; idx < CI_ * V_; idx += 256) {
    int o = idx / V_, v = idx % V_;
    float af = bm1[o], ab = bm2[o];
    for (int i = 0; i < CIN_; i++) {
      af += Wm1[o * CIN_ + i] * MfL[i][v];
      ab += Wm2[o * CIN_ + i] * MbL[i][v];
    }
    xfL[o][v] = af; xbL[o][v] = ab;
  }
  __syncthreads();
  for (int idx = tid; idx < COUT_ * V_; idx += 256) {
    int c = idx / V_, u = idx % V_;
    float p = 0.f, q = 0.f;
    for (int i = 0; i < CI_; i++) {
      p += Wm3[c * CI_ + i] * xbL[i][u];
      q += Wm3[c * CI_ + i] * xfL[i][u];
    }
    PL[idx] = p; QL[idx] = q;
  }
  __syncthreads();
  float al = alpha[0];
  for (int r = tid; r < COUT_ * V_; r += 256) {
    int c = r / V_, u = r % V_;
    float pv = PL[r] + bm3[c];
    float acc = 0.f;
    u16* dst = rdws + ((size_t)(n * COUT_ + c) * 25 + u) * 32;
    for (int w = 0; w < 25; w++) {
      float val = al * tanhf(pv - QL[c * V_ + w]);
      dst[w] = f2bf(val);
      acc += val;
    }
    for (int w = 25; w < 32; w++) dst[w] = 0;
    float yb = 0.f;
    for (int s = 0; s < 3; s++) yb += bp[s * COUT_ + c] * rsumL[s][u];
    biasws[(size_t)(n * COUT_ + c) * 25 + u] = bm4[c] * acc + yb;
  }
}

// ---------------- K3: fused MFMA main pass ----------------
// Stage A: [640x64]@[64 x 400pos] bf16 MFMA (K=64, 2 ksteps), per 16-channel group, split in 2 slab-halves.
// Stage B: per (n,c): y[16t x 25u] = Xp_all[16t x 128kk] @ [BsT(3x32) ; Rd_c(32)] (K=128, 4 ksteps).
// Output: packed u32 per element: lo = y bf16 (stage B), hi = d bf16 (stage A). Stats -> partials.
__global__ __launch_bounds__(256, 2) void k_main(
    const float* __restrict__ x, const u16* __restrict__ w5, const u16* __restrict__ bst,
    const u16* __restrict__ rdws, const float* __restrict__ biasws,
    u16* __restrict__ out16, float* __restrict__ partials) {
  // union region: phase0 x-staging (416 rows x 72 bf16 = 59904 B)  /  XpL (16c x 16t x 72 bf16 = 36864 B)
  __shared__ __align__(16) char smem[59904];
  __shared__ float statsL[512];
  const int tid = threadIdx.x;
  const int w = tid >> 6, l = tid & 63;
  const int lc = l & 15, lq = l >> 4;
  const int n = blockIdx.y, tc = blockIdx.x, t0 = tc * 16;

  // phase 0a: stage x tile -> LDS, transposed [p][k] bf16 (row stride 72 el = 144 B)
  {
    u32* xslw = (u32*)smem;
    const float* xb = x + (size_t)n * CIN_ * T_ * V_ + (size_t)t0 * V_;
    for (int idx = tid; idx < 32 * 416; idx += 256) {
      int i2 = idx / 416, p = idx - i2 * 416;
      float a = 0.f, b = 0.f;
      if (p < 400) {
        a = xb[(size_t)(2 * i2)     * (T_ * V_) + p];
        b = xb[(size_t)(2 * i2 + 1) * (T_ * V_) + p];
      }
      xslw[p * 36 + i2] = ((u32)f2bf(b) << 16) | (u32)f2bf(a);
    }
  }
  // BsT B-frags (shared by all groups): bw[s][utile]
  bf16x8 bw[3][2];
  #pragma unroll
  for (int s = 0; s < 3; s++)
    #pragma unroll
    for (int ut = 0; ut < 2; ut++)
      bw[s][ut] = *(const bf16x8*)(bst + (s * 32 + ut * 16 + lc) * 32 + lq * 8);
  __syncthreads();

  // phase 0c: x B-frags -> registers (wave w owns ptiles w, w+4, ...)
  bf16x8 xf[7][2] = {};
  #pragma unroll
  for (int pi = 0; pi < 7; pi++) {
    int pt = w + pi * 4;
    if (pt < 26) {
      #pragma unroll
      for (int ks = 0; ks < 2; ks++)
        xf[pi][ks] = *(const bf16x8*)((const u16*)smem + (pt * 16 + lc) * 72 + ks * 32 + lq * 8);
    }
  }
  __syncthreads();

  // phase 0e: zero XpL region (pads must be 0) + statsL
  {
    uint4 z4 = {0, 0, 0, 0};
    uint4* q = (uint4*)smem;
    for (int idx = tid; idx < 2304; idx += 256) q[idx] = z4;
    statsL[tid] = 0.f; statsL[tid + 256] = 0.f;
  }
  __syncthreads();

  u16* xpl = (u16*)smem;   // [c16][t16][72]: slot0 32 + slot1 32 + pad 8
  const f32x4 zz = {0.f, 0.f, 0.f, 0.f};

  for (int g = 0; g < 8; g++) {
    const int c0 = g * 16;
    f32x4 acc[4][2];
    #pragma unroll
    for (int cl = 0; cl < 4; cl++) { acc[cl][0] = zz; acc[cl][1] = zz; }
    float ds[4] = {0.f, 0.f, 0.f, 0.f}, dq[4] = {0.f, 0.f, 0.f, 0.f};

    #pragma unroll
    for (int h = 0; h < 2; h++) {
      const int nsl = h ? 3 : 2;
      // ---- stage A: slabs h*2 .. h*2+nsl-1 ----
      bf16x8 af[3][2];
      #pragma unroll
      for (int si = 0; si < 3; si++) if (si < nsl) {
        int sl = h * 2 + si;
        #pragma unroll
        for (int ks = 0; ks < 2; ks++)
          af[si][ks] = *(const bf16x8*)(w5 + ((sl * 128 + c0 + lc) * 64 + ks * 32 + lq * 8));
      }
      #pragma unroll
      for (int pi = 0; pi < 7; pi++) {
        int pt = w + pi * 4;
        if (pt >= 26) continue;
        f32x4 pa[3];
        #pragma unroll
        for (int si = 0; si < 3; si++) if (si < nsl) {
          pa[si] = MFMA16(af[si][0], xf[pi][0], zz);
          pa[si] = MFMA16(af[si][1], xf[pi][1], pa[si]);
        }
        int p = pt * 16 + lc;
        if (p < 400) {
          u32 up = (u32)p, t = up / 25u, v = up - t * 25u;
          #pragma unroll
          for (int si = 0; si < 3; si++) if (si < nsl) {
            int sl = h * 2 + si;
            if (sl < 4) {
              int slot = sl & 1;
              u16* dst = xpl + (4 * lq) * 1152 + t * 72 + slot * 32 + v;
              #pragma unroll
              for (int r = 0; r < 4; r++) dst[r * 1152] = f2bf(pa[si][r]);
            } else {  // d slab -> hi u16 of packed output + stats
              size_t ob = (((size_t)(n * COUT_ + c0 + 4 * lq) * T_ + t0 + t) * V_ + v) * 2 + 1;
              #pragma unroll
              for (int r = 0; r < 4; r++) {
                float dv = pa[si][r];
                out16[ob + (size_t)r * (T_ * V_ * 2)] = f2bf(dv);
                ds[r] += dv; dq[r] += dv * dv;
              }
            }
          }
        }
      }
      if (h == 1) {  // d-stats: reduce over the 16 col-lanes, atomically add per channel
        #pragma unroll
        for (int r = 0; r < 4; r++) {
          float a = ds[r], b = dq[r];
          #pragma unroll
          for (int off = 1; off < 16; off <<= 1) { a += __shfl_xor(a, off); b += __shfl_xor(b, off); }
          if (lc == 0) {
            atomicAdd(&statsL[(c0 + 4 * lq + r) * 4 + 2], a);
            atomicAdd(&statsL[(c0 + 4 * lq + r) * 4 + 3], b);
          }
        }
      }
      __syncthreads();

      // ---- stage B: ksteps h*2, h*2+1 (wave owns 4 consecutive channels) ----
      {
        bf16x8 rdf0[4], rdf1[4];
        if (h == 1) {
          #pragma unroll
          for (int cl = 0; cl < 4; cl++) {
            size_t rb = (size_t)(n * COUT_ + c0 + w * 4 + cl) * 25;
            rdf0[cl] = *(const bf16x8*)(rdws + (rb + lc) * 32 + lq * 8);
            int u1c = (lc + 16 < 25) ? lc + 16 : 24;
            rdf1[cl] = *(const bf16x8*)(rdws + (rb + u1c) * 32 + lq * 8);
          }
        }
        #pragma unroll
        for (int cl = 0; cl < 4; cl++) {
          int clocal = w * 4 + cl;
          #pragma unroll
          for (int kl = 0; kl < 2; kl++) {
            bf16x8 aX = *(const bf16x8*)(xpl + clocal * 1152 + lc * 72 + kl * 32 + lq * 8);
            int kk = h * 2 + kl;
            bf16x8 b0, b1;
            if (kk < 3) { b0 = bw[kk][0]; b1 = bw[kk][1]; }
            else        { b0 = rdf0[cl];  b1 = rdf1[cl]; }
            acc[cl][0] = MFMA16(aX, b0, acc[cl][0]);
            acc[cl][1] = MFMA16(aX, b1, acc[cl][1]);
          }
        }
      }
      if (h == 1) {  // epilogue: bias, store y (lo u16), stats
        #pragma unroll
        for (int cl = 0; cl < 4; cl++) {
          int c = c0 + w * 4 + cl;
          size_t bb = (size_t)(n * COUT_ + c) * 25;
          float bias0 = biasws[bb + lc];
          int u1 = lc + 16; bool v1 = u1 < 25;
          float bias1 = biasws[bb + (v1 ? u1 : 24)];
          size_t ob = ((size_t)(n * COUT_ + c) * T_ + t0) * V_;
          float sy = 0.f, sq = 0.f;
          #pragma unroll
          for (int r = 0; r < 4; r++) {
            int t = 4 * lq + r;
            float y0 = acc[cl][0][r] + bias0;
            out16[(ob + t * 25 + lc) * 2] = f2bf(y0);
            sy += y0; sq += y0 * y0;
            float y1 = acc[cl][1][r] + bias1;
            if (v1) {
              out16[(ob + t * 25 + u1) * 2] = f2bf(y1);
              sy += y1; sq += y1 * y1;
            }
          }
          #pragma unroll
          for (int off = 1; off < 64; off <<= 1) { sy += __shfl_xor(sy, off); sq += __shfl_xor(sq, off); }
          if (l == 0) { atomicAdd(&statsL[c * 4 + 0], sy); atomicAdd(&statsL[c * 4 + 1], sq); }
        }
      }
      __syncthreads();
    }
  }
  int bflat = blockIdx.y * 16 + blockIdx.x;
  for (int j = tid; j < 512; j += 256) partials[(size_t)j * 1024 + bflat] = statsL[j];
}

// ---------------- K4a: reduce partials [512][1024] -> colsum[512] ----------------
__global__ __launch_bounds__(256) void k_stats1(const float* __restrict__ partials, float* __restrict__ colsum) {
  int w = threadIdx.x >> 6, l = threadIdx.x & 63;
  for (int ci = 0; ci < 8; ci++) {
    int j = blockIdx.x * 32 + w * 8 + ci;
    float s = 0.f;
    for (int it = 0; it < 16; it++) s += partials[(size_t)j * 1024 + it * 64 + l];
    #pragma unroll
    for (int off = 1; off < 64; off <<= 1) s += __shfl_xor(s, off);
    if (l == 0) colsum[j] = s;
  }
}

// ---------------- K4b: BN affine params ----------------
__global__ __launch_bounds__(128) void k_stats2(
    const float* __restrict__ colsum,
    const float* __restrict__ bn_g, const float* __restrict__ bn_b,
    const float* __restrict__ dn_g, const float* __restrict__ dn_b,
    float* __restrict__ params) {
  int c = threadIdx.x;
  float sy = colsum[c * 4], syy = colsum[c * 4 + 1], sd = colsum[c * 4 + 2], sdd = colsum[c * 4 + 3];
  float muY = sy / CNT_, varY = syy / CNT_ - muY * muY;
  float muD = sd / CNT_, varD = sdd / CNT_ - muD * muD;
  float sY = bn_g[c] * rsqrtf(varY + EPS_);
  float sD = dn_g[c] * rsqrtf(varD + EPS_);
  float off = bn_b[c] - muY * sY + dn_b[c] - muD * sD;
  params[c * 4 + 0] = sY; params[c * 4 + 1] = sD; params[c * 4 + 2] = off;
}

// ---------------- K5: in-place finalize: relu(y*sY + d*sD + off) ----------------
__global__ __launch_bounds__(256) void k_final(u32* __restrict__ io, const float* __restrict__ params) {
  int slab = blockIdx.x;             // n*COUT_ + c
  int c = slab & (COUT_ - 1);
  float sY = params[c * 4], sD = params[c * 4 + 1], off = params[c * 4 + 2];
  size_t base = (size_t)slab * (T_ * V_);
  #pragma unroll 5
  for (int j = 0; j < 25; j++) {
    size_t idx = base + j * 256 + threadIdx.x;
    u32 w = io[idx];
    float y = bf2f((u16)(w & 0xffffu));
    float d = bf2f((u16)(w >> 16));
    float val = fmaf(y, sY, fmaf(d, sD, off));
    io[idx] = __float_as_uint(fmaxf(val, 0.0f));
  }
}

extern "C" void kernel_launch(void* const* d_in, const int* in_sizes, int n_in,
                              void* d_out, int out_size, void* d_ws, size_t ws_size,
                              hipStream_t stream) {
  const float* x    = (const float*)d_in[0];
  const float* A    = (const float*)d_in[1];
  const float* Al   = (const float*)d_in[2];
  const float* Wp   = (const float*)d_in[3];
  const float* bp   = (const float*)d_in[4];
  const float* Wm1  = (const float*)d_in[5];
  const float* bm1  = (const float*)d_in[6];
  const float* Wm2  = (const float*)d_in[7];
  const float* bm2  = (const float*)d_in[8];
  const float* Wm3  = (const float*)d_in[9];
  const float* bm3  = (const float*)d_in[10];
  const float* Wm4  = (const float*)d_in[11];
  const float* bm4  = (const float*)d_in[12];
  const float* alpha= (const float*)d_in[13];
  const float* bn_g = (const float*)d_in[14];
  const float* bn_b = (const float*)d_in[15];
  const float* dW   = (const float*)d_in[16];
  const float* dn_g = (const float*)d_in[17];
  const float* dn_b = (const float*)d_in[18];

  // workspace layout (bytes, 16B-aligned), total ~16.9 MB
  char* ws = (char*)d_ws;
  float* mf       = (float*)(ws + 0);              //   409,600
  float* mb       = (float*)(ws + 409600);         //   409,600
  u16*   rdws     = (u16*)  (ws + 819200);         // 13,107,200  [n][128][25][32] bf16
  float* biasws   = (float*)(ws + 13926400);       //   819,200   [n][128][25]
  u16*   w5       = (u16*)  (ws + 14745600);       //    81,920   [640][64] bf16
  u16*   bstw     = (u16*)  (ws + 14827520);       //     6,144   [3][32][32] bf16
  float* partials = (float*)(ws + 14833664);       // 2,097,152   [512][1024]
  float* colsum   = (float*)(ws + 16930816);       //     2,048
  float* params   = (float*)(ws + 16932864);       //     2,048

  k_pack <<<dim3(1),       dim3(256), 0, stream>>>(Wp, Wm4, dW, A, Al, w5, bstw);
  k_means<<<dim3(64, 64),  dim3(256), 0, stream>>>(x, mf, mb);
  k_rd   <<<dim3(64),      dim3(256), 0, stream>>>(mf, mb, Wm1, bm1, Wm2, bm2, Wm3, bm3,
                                                   bm4, alpha, A, Al, bp, rdws, biasws);
  k_main <<<dim3(16, 64),  dim3(256), 0, stream>>>(x, w5, bstw, rdws, biasws,
                                                   (u16*)d_out, partials);
  k_stats1<<<dim3(16),     dim3(256), 0, stream>>>(partials, colsum);
  k_stats2<<<dim3(1),      dim3(128), 0, stream>>>(colsum, bn_g, bn_b, dn_g, dn_b, params);
  k_final<<<dim3(64 * 128),dim3(256), 0, stream>>>((u32*)d_out, params);
}